// Round 7
// baseline (1288.853 us; speedup 1.0000x reference)
//
#include <hip/hip_runtime.h>

// Spatialize via MFMA, v4 = v3 + barriers WITHOUT vmcnt drain.
// v3's __syncthreads() made the compiler drain vmcnt(0) at every chunk barrier,
// exposing full global-load latency 321 times. v4 uses raw s_barrier with only
// lgkmcnt(0) (LDS ordering), so A/x global loads stay in flight across barriers
// (T3/T4 counted-vmcnt pattern); x is prefetched 2 chunks ahead, A 1 chunk.
// Indexing/numerics identical to v3 (same f2bf, chunk order, MFMA shape).

#define K_TAPS  10000
#define T_LEN   150000
#define OUT_T0  12500
#define OUT_T1  137500
#define OUT_LEN 125000
#define BATCH   64

#define TM    256                 // output times per block
#define KC    32                  // K per chunk
#define D0    10016               // t0 - p_start
#define NC    321                 // chunks
#define NMAX  (D0 + TM - 1)       // 10271
#define NTAB  10528               // elems per rho-copy
#define CS_BYTES  (NTAB * 2)      // 21056
#define CH_STRIDE (8 * CS_BYTES)  // 168448
#define XCOLS 40                  // 32 + 8 pad (80B pitch)

typedef short  bf16x8 __attribute__((ext_vector_type(8)));
typedef float  f32x4  __attribute__((ext_vector_type(4)));

__device__ __forceinline__ unsigned f2bf(float f) {
    unsigned u = __builtin_bit_cast(unsigned, f);
    return (u + 0x7FFFu + ((u >> 16) & 1u)) >> 16;   // RNE
}

__device__ __forceinline__ uint2 pack4(float4 v) {
    uint2 w;
    w.x = f2bf(v.x) | (f2bf(v.y) << 16);
    w.y = f2bf(v.z) | (f2bf(v.w) << 16);
    return w;
}

// tab[ch][rho][m] = hpad[NMAX - (m + rho)]  (zero outside [0,K_TAPS))
__global__ __launch_bounds__(256) void build_tab(
    const float* __restrict__ ir, ushort* __restrict__ tab)
{
    const int m = blockIdx.x * 256 + threadIdx.x;
    if (m >= NTAB) return;
    const int y   = blockIdx.y;        // 0..15
    const int ch  = y >> 3;
    const int rho = y & 7;
    const int d   = NMAX - m - rho;
    const float v = (d >= 0 && d < K_TAPS) ? ir[2 * d + ch] : 0.f;
    tab[(size_t)ch * (8 * NTAB) + (size_t)rho * NTAB + m] = (ushort)f2bf(v);
}

struct Afrags { bf16x8 a0, a1, a2, a3; };

__device__ __forceinline__ void load_A(Afrags& A, const char* tA, int aoff) {
    A.a0 = *(const bf16x8*)(tA + aoff);
    A.a1 = *(const bf16x8*)(tA + aoff - 32);
    A.a2 = *(const bf16x8*)(tA + aoff - 64);
    A.a3 = *(const bf16x8*)(tA + aoff - 96);
}

__device__ __forceinline__ void do_chunk(const Afrags& A,
                                         const ushort (*xbuf)[XCOLS],
                                         int lrow, int koff, f32x4 acc[4][4])
{
    bf16x8 b0 = *(const bf16x8*)&xbuf[ 0 + lrow][koff];
    bf16x8 b1 = *(const bf16x8*)&xbuf[16 + lrow][koff];
    bf16x8 b2 = *(const bf16x8*)&xbuf[32 + lrow][koff];
    bf16x8 b3 = *(const bf16x8*)&xbuf[48 + lrow][koff];
#define MM(mt, AF)                                                              \
    acc[mt][0] = __builtin_amdgcn_mfma_f32_16x16x32_bf16(AF, b0, acc[mt][0], 0, 0, 0); \
    acc[mt][1] = __builtin_amdgcn_mfma_f32_16x16x32_bf16(AF, b1, acc[mt][1], 0, 0, 0); \
    acc[mt][2] = __builtin_amdgcn_mfma_f32_16x16x32_bf16(AF, b2, acc[mt][2], 0, 0, 0); \
    acc[mt][3] = __builtin_amdgcn_mfma_f32_16x16x32_bf16(AF, b3, acc[mt][3], 0, 0, 0);
    MM(0, A.a0) MM(1, A.a1) MM(2, A.a2) MM(3, A.a3)
#undef MM
}

// lgkmcnt(0) (LDS ordering only) + raw barrier: global loads stay in flight.
__device__ __forceinline__ void lds_barrier() {
    asm volatile("s_waitcnt lgkmcnt(0)" ::: "memory");
    __builtin_amdgcn_s_barrier();
}

__global__ __launch_bounds__(512, 4) void spatialize_mfma4(
    const float* __restrict__ x, const ushort* __restrict__ tab,
    float* __restrict__ out)
{
    __shared__ ushort xb[2][BATCH][XCOLS];   // 10240 B

    const int tid  = threadIdx.x;
    const int lane = tid & 63;
    const int wid  = tid >> 6;          // 8 waves
    const int ch   = wid >> 2;          // channel split across waves
    const int wm   = wid & 3;           // 4 m-tiles of 64 times
    const int lrow = lane & 15;
    const int koff = (lane >> 4) * 8;

    // bijective XCD-chunked swizzle
    const int nwg = gridDim.x;
    const int q8 = nwg >> 3, r8 = nwg & 7;
    const int xcd = blockIdx.x & 7, loc = blockIdx.x >> 3;
    const int tile = (xcd < r8 ? xcd * (q8 + 1) : r8 * (q8 + 1) + (xcd - r8) * q8) + loc;

    const int t0      = OUT_T0 + tile * TM;
    const int p_start = t0 - D0;        // >= 2484

    // A addressing: s = NMAX - D0 - wm*64 - lrow + koff + 32*i - 16*mt
    // byte(s) = (s&7)*CS_BYTES + (s>>3)*16 ; chunk: +64 ; mt: -32 (rho invariant)
    const int s0 = NMAX - D0 - wm * 64 - lrow + koff;    // >= 48
    int aoff = (s0 & 7) * CS_BYTES + ((s0 >> 3) << 4);
    const char* tA = (const char*)tab + (size_t)ch * CH_STRIDE;

    // x staging: 512 thr -> 64 rows x 8 quads of 4 f32 (uint2 LDS write)
    const int srow = tid >> 3;
    const int sc4  = (tid & 7) * 4;
    const float* xrow = x + (size_t)srow * T_LEN + p_start + sc4;

    // ---- prologue: chunk 0 staged; A chunk 0 + x chunk 1 in flight ----
    Afrags A0, A1;
    load_A(A0, tA, aoff);
    *(uint2*)&xb[0][srow][sc4] = pack4(*(const float4*)xrow);
    float4 xvA = *(const float4*)(xrow + KC);   // chunk 1, consumed round 0
    float4 xvB;
    lds_barrier();

    f32x4 acc[4][4];
#pragma unroll
    for (int mt = 0; mt < 4; ++mt)
#pragma unroll
        for (int nt = 0; nt < 4; ++nt)
            acc[mt][nt] = (f32x4){0.f, 0.f, 0.f, 0.f};

    // manual ping-pong; x prefetch depth 2, A depth 1, no vmcnt drain in loop
    int i = 0;
    while (true) {
        // ---- even chunk i : buffer 0, frags A0, pending x(i+1) in xvA ----
        const bool m1 = (i + 1 < NC);
        const bool m2 = (i + 2 < NC);
        if (m1) { aoff += 64; load_A(A1, tA, aoff); }          // A for i+1
        if (m2) xvB = *(const float4*)(xrow + (i + 2) * KC);   // x for i+2
        if (m1) *(uint2*)&xb[1][srow][sc4] = pack4(xvA);       // stage i+1
        do_chunk(A0, xb[0], lrow, koff, acc);
        lds_barrier();
        if (!m1) break;

        // ---- odd chunk i+1 : buffer 1, frags A1, pending x(i+2) in xvB ----
        const bool m3 = (i + 3 < NC);
        if (m2) { aoff += 64; load_A(A0, tA, aoff); }          // A for i+2
        if (m3) xvA = *(const float4*)(xrow + (i + 3) * KC);   // x for i+3
        if (m2) *(uint2*)&xb[0][srow][sc4] = pack4(xvB);       // stage i+2
        do_chunk(A1, xb[1], lrow, koff, acc);
        lds_barrier();
        if (!m2) break;
        i += 2;
    }

    // ---- epilogue: D frag col=lane&15 -> batch, row=(lane>>4)*4+reg -> time ----
    const int r4 = (lane >> 4) * 4;
#pragma unroll
    for (int mt = 0; mt < 4; ++mt) {
        const int t4 = t0 + wm * 64 + mt * 16 + r4;
        if (t4 < OUT_T1) {   // OUT_T1 % 4 == 0 -> whole float4 in or out
#pragma unroll
            for (int nt = 0; nt < 4; ++nt) {
                const int b = nt * 16 + lrow;
                const f32x4 a = acc[mt][nt];
                *(float4*)&out[(size_t)b * (2 * OUT_LEN) +
                               (size_t)ch * OUT_LEN + (t4 - OUT_T0)] =
                    make_float4(a[0], a[1], a[2], a[3]);
            }
        }
    }
}

extern "C" void kernel_launch(void* const* d_in, const int* in_sizes, int n_in,
                              void* d_out, int out_size, void* d_ws, size_t ws_size,
                              hipStream_t stream)
{
    (void)in_sizes; (void)n_in; (void)out_size; (void)ws_size; // needs >= 337 KB
    const float* x  = (const float*)d_in[0];
    const float* ir = (const float*)d_in[1];
    float* out      = (float*)d_out;
    ushort* tab     = (ushort*)d_ws;

    dim3 gt((NTAB + 255) / 256, 16);
    hipLaunchKernelGGL(build_tab, gt, dim3(256), 0, stream, ir, tab);

    dim3 grid((OUT_LEN + TM - 1) / TM);   // 489
    hipLaunchKernelGGL(spatialize_mfma4, grid, dim3(512), 0, stream, x, tab, out);
}

// Round 8
// 656.696 us; speedup vs baseline: 1.9626x; 1.9626x over previous
//
#include <hip/hip_runtime.h>

// Spatialize via MFMA, v5 = v3's exact loop/register structure with ONLY the
// barrier changed: __syncthreads() (drains vmcnt(0) -> 321 exposed-latency
// stalls) replaced by {s_waitcnt lgkmcnt(0); sched_barrier(0); s_barrier}.
// No "memory" clobber (v4's clobber + depth-2 prefetch caused ~2 GB/dispatch
// scratch spill traffic: WRITE_SIZE 70MB->1.1GB). Global A/x loads stay in
// flight across barriers; LDS producer->consumer ordering preserved by the
// lgkmcnt wait. Numerics identical to v3/v4.

#define K_TAPS  10000
#define T_LEN   150000
#define OUT_T0  12500
#define OUT_T1  137500
#define OUT_LEN 125000
#define BATCH   64

#define TM    256                 // output times per block
#define KC    32                  // K per chunk
#define D0    10016               // t0 - p_start
#define NC    321                 // chunks
#define NMAX  (D0 + TM - 1)       // 10271
#define NTAB  10528               // elems per rho-copy
#define CS_BYTES  (NTAB * 2)      // 21056
#define CH_STRIDE (8 * CS_BYTES)  // 168448
#define XCOLS 40                  // 32 + 8 pad (80B pitch)

typedef short  bf16x8 __attribute__((ext_vector_type(8)));
typedef float  f32x4  __attribute__((ext_vector_type(4)));

__device__ __forceinline__ unsigned f2bf(float f) {
    unsigned u = __builtin_bit_cast(unsigned, f);
    return (u + 0x7FFFu + ((u >> 16) & 1u)) >> 16;   // RNE
}

__device__ __forceinline__ uint2 pack4(float4 v) {
    uint2 w;
    w.x = f2bf(v.x) | (f2bf(v.y) << 16);
    w.y = f2bf(v.z) | (f2bf(v.w) << 16);
    return w;
}

// tab[ch][rho][m] = hpad[NMAX - (m + rho)]  (zero outside [0,K_TAPS))
__global__ __launch_bounds__(256) void build_tab(
    const float* __restrict__ ir, ushort* __restrict__ tab)
{
    const int m = blockIdx.x * 256 + threadIdx.x;
    if (m >= NTAB) return;
    const int y   = blockIdx.y;        // 0..15
    const int ch  = y >> 3;
    const int rho = y & 7;
    const int d   = NMAX - m - rho;
    const float v = (d >= 0 && d < K_TAPS) ? ir[2 * d + ch] : 0.f;
    tab[(size_t)ch * (8 * NTAB) + (size_t)rho * NTAB + m] = (ushort)f2bf(v);
}

struct Afrags { bf16x8 a0, a1, a2, a3; };

__device__ __forceinline__ void load_A(Afrags& A, const char* tA, int aoff) {
    A.a0 = *(const bf16x8*)(tA + aoff);
    A.a1 = *(const bf16x8*)(tA + aoff - 32);
    A.a2 = *(const bf16x8*)(tA + aoff - 64);
    A.a3 = *(const bf16x8*)(tA + aoff - 96);
}

__device__ __forceinline__ void do_chunk(const Afrags& A,
                                         const ushort (*xbuf)[XCOLS],
                                         int lrow, int koff, f32x4 acc[4][4])
{
    bf16x8 b0 = *(const bf16x8*)&xbuf[ 0 + lrow][koff];
    bf16x8 b1 = *(const bf16x8*)&xbuf[16 + lrow][koff];
    bf16x8 b2 = *(const bf16x8*)&xbuf[32 + lrow][koff];
    bf16x8 b3 = *(const bf16x8*)&xbuf[48 + lrow][koff];
#define MM(mt, AF)                                                              \
    acc[mt][0] = __builtin_amdgcn_mfma_f32_16x16x32_bf16(AF, b0, acc[mt][0], 0, 0, 0); \
    acc[mt][1] = __builtin_amdgcn_mfma_f32_16x16x32_bf16(AF, b1, acc[mt][1], 0, 0, 0); \
    acc[mt][2] = __builtin_amdgcn_mfma_f32_16x16x32_bf16(AF, b2, acc[mt][2], 0, 0, 0); \
    acc[mt][3] = __builtin_amdgcn_mfma_f32_16x16x32_bf16(AF, b3, acc[mt][3], 0, 0, 0);
    MM(0, A.a0) MM(1, A.a1) MM(2, A.a2) MM(3, A.a3)
#undef MM
}

// LDS-only ordering barrier: wave's ds ops complete (visible), then barrier.
// NO memory clobber, NO vmcnt drain -> global loads stay in flight across it.
__device__ __forceinline__ void lds_barrier() {
    asm volatile("s_waitcnt lgkmcnt(0)");
    __builtin_amdgcn_sched_barrier(0);
    __builtin_amdgcn_s_barrier();
}

__global__ __launch_bounds__(512, 4) void spatialize_mfma5(
    const float* __restrict__ x, const ushort* __restrict__ tab,
    float* __restrict__ out)
{
    __shared__ ushort xb[2][BATCH][XCOLS];   // 10240 B

    const int tid  = threadIdx.x;
    const int lane = tid & 63;
    const int wid  = tid >> 6;          // 8 waves
    const int ch   = wid >> 2;          // channel split across waves
    const int wm   = wid & 3;           // 4 m-tiles of 64 times
    const int lrow = lane & 15;
    const int koff = (lane >> 4) * 8;

    // bijective XCD-chunked swizzle
    const int nwg = gridDim.x;
    const int q8 = nwg >> 3, r8 = nwg & 7;
    const int xcd = blockIdx.x & 7, loc = blockIdx.x >> 3;
    const int tile = (xcd < r8 ? xcd * (q8 + 1) : r8 * (q8 + 1) + (xcd - r8) * q8) + loc;

    const int t0      = OUT_T0 + tile * TM;
    const int p_start = t0 - D0;        // >= 2484

    // A addressing: s = NMAX - D0 - wm*64 - lrow + koff + 32*i - 16*mt
    // byte(s) = (s&7)*CS_BYTES + (s>>3)*16 ; chunk: +64 ; mt: -32 (rho invariant)
    const int s0 = NMAX - D0 - wm * 64 - lrow + koff;    // >= 48
    int aoff = (s0 & 7) * CS_BYTES + ((s0 >> 3) << 4);
    const char* tA = (const char*)tab + (size_t)ch * CH_STRIDE;

    // x staging: 512 thr -> 64 rows x 8 quads of 4 f32 (uint2 LDS write)
    const int srow = tid >> 3;
    const int sc4  = (tid & 7) * 4;
    const float* xrow = x + (size_t)srow * T_LEN + p_start + sc4;

    // stage chunk 0, preload A chunk 0
    *(uint2*)&xb[0][srow][sc4] = pack4(*(const float4*)xrow);
    Afrags A0, A1;
    load_A(A0, tA, aoff);
    lds_barrier();

    f32x4 acc[4][4];
#pragma unroll
    for (int mt = 0; mt < 4; ++mt)
#pragma unroll
        for (int nt = 0; nt < 4; ++nt)
            acc[mt][nt] = (f32x4){0.f, 0.f, 0.f, 0.f};

    // manual ping-pong over chunk pairs (NC = 321, odd -> last even chunk breaks)
    int i = 0;
    while (true) {
        // ---- even chunk i : buffer 0, frags A0 ----
        const bool m1 = (i + 1 < NC);
        float4 xv;
        if (m1) {
            aoff += 64;
            load_A(A1, tA, aoff);                       // prefetch chunk i+1
            xv = *(const float4*)(xrow + (i + 1) * KC);
        }
        do_chunk(A0, xb[0], lrow, koff, acc);
        if (m1) *(uint2*)&xb[1][srow][sc4] = pack4(xv);
        lds_barrier();
        if (!m1) break;

        // ---- odd chunk i+1 : buffer 1, frags A1 ----
        const bool m2 = (i + 2 < NC);
        if (m2) {
            aoff += 64;
            load_A(A0, tA, aoff);                       // prefetch chunk i+2
            xv = *(const float4*)(xrow + (i + 2) * KC);
        }
        do_chunk(A1, xb[1], lrow, koff, acc);
        if (m2) *(uint2*)&xb[0][srow][sc4] = pack4(xv);
        lds_barrier();
        if (!m2) break;
        i += 2;
    }

    // ---- epilogue: D frag col=lane&15 -> batch, row=(lane>>4)*4+reg -> time ----
    const int r4 = (lane >> 4) * 4;
#pragma unroll
    for (int mt = 0; mt < 4; ++mt) {
        const int t4 = t0 + wm * 64 + mt * 16 + r4;
        if (t4 < OUT_T1) {   // OUT_T1 % 4 == 0 -> whole float4 in or out
#pragma unroll
            for (int nt = 0; nt < 4; ++nt) {
                const int b = nt * 16 + lrow;
                const f32x4 a = acc[mt][nt];
                *(float4*)&out[(size_t)b * (2 * OUT_LEN) +
                               (size_t)ch * OUT_LEN + (t4 - OUT_T0)] =
                    make_float4(a[0], a[1], a[2], a[3]);
            }
        }
    }
}

extern "C" void kernel_launch(void* const* d_in, const int* in_sizes, int n_in,
                              void* d_out, int out_size, void* d_ws, size_t ws_size,
                              hipStream_t stream)
{
    (void)in_sizes; (void)n_in; (void)out_size; (void)ws_size; // needs >= 337 KB
    const float* x  = (const float*)d_in[0];
    const float* ir = (const float*)d_in[1];
    float* out      = (float*)d_out;
    ushort* tab     = (ushort*)d_ws;

    dim3 gt((NTAB + 255) / 256, 16);
    hipLaunchKernelGGL(build_tab, gt, dim3(256), 0, stream, ir, tab);

    dim3 grid((OUT_LEN + TM - 1) / TM);   // 489
    hipLaunchKernelGGL(spatialize_mfma5, grid, dim3(512), 0, stream, x, tab, out);
}

// Round 10
// 573.086 us; speedup vs baseline: 2.2490x; 1.1459x over previous
//
#include <hip/hip_runtime.h>

// Spatialize via MFMA, v6 = v5 with x-load consumption deferred one iteration
// ("write-at-top"). v5 issued x(i+1) at the top of chunk i's body and consumed
// it at the bottom of the SAME body -> issue->use ~400 cyc < HBM latency ->
// every chunk stalled on x right before the barrier, and the barrier spread
// the slowest wave's stall to all 8 waves, 321 times. v6 writes pack4(xv)
// (loaded one full iteration ago) FIRST, then issues the next x load into the
// same registers (live ranges don't overlap -> register-neutral). Buffers:
// write xb[(i+1)&1], read xb[i&1]. Numerics identical to v3/v4/v5.

#define K_TAPS  10000
#define T_LEN   150000
#define OUT_T0  12500
#define OUT_T1  137500
#define OUT_LEN 125000
#define BATCH   64

#define TM    256                 // output times per block
#define KC    32                  // K per chunk
#define D0    10016               // t0 - p_start
#define NC    321                 // chunks
#define NMAX  (D0 + TM - 1)       // 10271
#define NTAB  10528               // elems per rho-copy
#define CS_BYTES  (NTAB * 2)      // 21056
#define CH_STRIDE (8 * CS_BYTES)  // 168448
#define XCOLS 40                  // 32 + 8 pad (80B pitch)

typedef short  bf16x8 __attribute__((ext_vector_type(8)));
typedef float  f32x4  __attribute__((ext_vector_type(4)));

__device__ __forceinline__ unsigned f2bf(float f) {
    unsigned u = __builtin_bit_cast(unsigned, f);
    return (u + 0x7FFFu + ((u >> 16) & 1u)) >> 16;   // RNE
}

__device__ __forceinline__ uint2 pack4(float4 v) {
    uint2 w;
    w.x = f2bf(v.x) | (f2bf(v.y) << 16);
    w.y = f2bf(v.z) | (f2bf(v.w) << 16);
    return w;
}

// tab[ch][rho][m] = hpad[NMAX - (m + rho)]  (zero outside [0,K_TAPS))
__global__ __launch_bounds__(256) void build_tab(
    const float* __restrict__ ir, ushort* __restrict__ tab)
{
    const int m = blockIdx.x * 256 + threadIdx.x;
    if (m >= NTAB) return;
    const int y   = blockIdx.y;        // 0..15
    const int ch  = y >> 3;
    const int rho = y & 7;
    const int d   = NMAX - m - rho;
    const float v = (d >= 0 && d < K_TAPS) ? ir[2 * d + ch] : 0.f;
    tab[(size_t)ch * (8 * NTAB) + (size_t)rho * NTAB + m] = (ushort)f2bf(v);
}

struct Afrags { bf16x8 a0, a1, a2, a3; };

__device__ __forceinline__ void load_A(Afrags& A, const char* tA, int aoff) {
    A.a0 = *(const bf16x8*)(tA + aoff);
    A.a1 = *(const bf16x8*)(tA + aoff - 32);
    A.a2 = *(const bf16x8*)(tA + aoff - 64);
    A.a3 = *(const bf16x8*)(tA + aoff - 96);
}

__device__ __forceinline__ void do_chunk(const Afrags& A,
                                         const ushort (*xbuf)[XCOLS],
                                         int lrow, int koff, f32x4 acc[4][4])
{
    bf16x8 b0 = *(const bf16x8*)&xbuf[ 0 + lrow][koff];
    bf16x8 b1 = *(const bf16x8*)&xbuf[16 + lrow][koff];
    bf16x8 b2 = *(const bf16x8*)&xbuf[32 + lrow][koff];
    bf16x8 b3 = *(const bf16x8*)&xbuf[48 + lrow][koff];
#define MM(mt, AF)                                                              \
    acc[mt][0] = __builtin_amdgcn_mfma_f32_16x16x32_bf16(AF, b0, acc[mt][0], 0, 0, 0); \
    acc[mt][1] = __builtin_amdgcn_mfma_f32_16x16x32_bf16(AF, b1, acc[mt][1], 0, 0, 0); \
    acc[mt][2] = __builtin_amdgcn_mfma_f32_16x16x32_bf16(AF, b2, acc[mt][2], 0, 0, 0); \
    acc[mt][3] = __builtin_amdgcn_mfma_f32_16x16x32_bf16(AF, b3, acc[mt][3], 0, 0, 0);
    MM(0, A.a0) MM(1, A.a1) MM(2, A.a2) MM(3, A.a3)
#undef MM
}

// LDS-only ordering barrier: wave's ds ops complete (visible), then barrier.
// NO memory clobber, NO vmcnt drain -> global loads stay in flight across it.
__device__ __forceinline__ void lds_barrier() {
    asm volatile("s_waitcnt lgkmcnt(0)");
    __builtin_amdgcn_sched_barrier(0);
    __builtin_amdgcn_s_barrier();
}

__global__ __launch_bounds__(512, 4) void spatialize_mfma6(
    const float* __restrict__ x, const ushort* __restrict__ tab,
    float* __restrict__ out)
{
    __shared__ ushort xb[2][BATCH][XCOLS];   // 10240 B

    const int tid  = threadIdx.x;
    const int lane = tid & 63;
    const int wid  = tid >> 6;          // 8 waves
    const int ch   = wid >> 2;          // channel split across waves
    const int wm   = wid & 3;           // 4 m-tiles of 64 times
    const int lrow = lane & 15;
    const int koff = (lane >> 4) * 8;

    // bijective XCD-chunked swizzle
    const int nwg = gridDim.x;
    const int q8 = nwg >> 3, r8 = nwg & 7;
    const int xcd = blockIdx.x & 7, loc = blockIdx.x >> 3;
    const int tile = (xcd < r8 ? xcd * (q8 + 1) : r8 * (q8 + 1) + (xcd - r8) * q8) + loc;

    const int t0      = OUT_T0 + tile * TM;
    const int p_start = t0 - D0;        // >= 2484

    // A addressing: s = NMAX - D0 - wm*64 - lrow + koff + 32*i - 16*mt
    // byte(s) = (s&7)*CS_BYTES + (s>>3)*16 ; chunk: +64 ; mt: -32 (rho invariant)
    const int s0 = NMAX - D0 - wm * 64 - lrow + koff;    // >= 48
    int aoff = (s0 & 7) * CS_BYTES + ((s0 >> 3) << 4);
    const char* tA = (const char*)tab + (size_t)ch * CH_STRIDE;

    // x staging: 512 thr -> 64 rows x 8 quads of 4 f32 (uint2 LDS write)
    const int srow = tid >> 3;
    const int sc4  = (tid & 7) * 4;
    const float* xrow = x + (size_t)srow * T_LEN + p_start + sc4;

    // ---- prologue: stage chunk 0 directly; x(1) in flight; A chunk 0 ----
    *(uint2*)&xb[0][srow][sc4] = pack4(*(const float4*)xrow);
    float4 xv = *(const float4*)(xrow + KC);   // x(1), consumed in iter 0
    Afrags A0, A1;
    load_A(A0, tA, aoff);
    lds_barrier();

    f32x4 acc[4][4];
#pragma unroll
    for (int mt = 0; mt < 4; ++mt)
#pragma unroll
        for (int nt = 0; nt < 4; ++nt)
            acc[mt][nt] = (f32x4){0.f, 0.f, 0.f, 0.f};

    // ping-pong over chunk pairs; x consumed one full iteration after issue
    int i = 0;
    while (true) {
        // ---- even chunk i : read xb[0], frags A0 ----
        const bool m1 = (i + 1 < NC);
        const bool m2 = (i + 2 < NC);
        if (m1) *(uint2*)&xb[1][srow][sc4] = pack4(xv);        // x(i+1), old load
        if (m2) xv = *(const float4*)(xrow + (i + 2) * KC);    // issue x(i+2)
        if (m1) { aoff += 64; load_A(A1, tA, aoff); }          // A chunk i+1
        do_chunk(A0, xb[0], lrow, koff, acc);
        lds_barrier();
        if (!m1) break;

        // ---- odd chunk i+1 : read xb[1], frags A1 ----
        const bool m3 = (i + 3 < NC);
        if (m2) *(uint2*)&xb[0][srow][sc4] = pack4(xv);        // x(i+2)
        if (m3) xv = *(const float4*)(xrow + (i + 3) * KC);    // issue x(i+3)
        if (m2) { aoff += 64; load_A(A0, tA, aoff); }          // A chunk i+2
        do_chunk(A1, xb[1], lrow, koff, acc);
        lds_barrier();
        if (!m2) break;
        i += 2;
    }

    // ---- epilogue: D frag col=lane&15 -> batch, row=(lane>>4)*4+reg -> time ----
    const int r4 = (lane >> 4) * 4;
#pragma unroll
    for (int mt = 0; mt < 4; ++mt) {
        const int t4 = t0 + wm * 64 + mt * 16 + r4;
        if (t4 < OUT_T1) {   // OUT_T1 % 4 == 0 -> whole float4 in or out
#pragma unroll
            for (int nt = 0; nt < 4; ++nt) {
                const int b = nt * 16 + lrow;
                const f32x4 a = acc[mt][nt];
                *(float4*)&out[(size_t)b * (2 * OUT_LEN) +
                               (size_t)ch * OUT_LEN + (t4 - OUT_T0)] =
                    make_float4(a[0], a[1], a[2], a[3]);
            }
        }
    }
}

extern "C" void kernel_launch(void* const* d_in, const int* in_sizes, int n_in,
                              void* d_out, int out_size, void* d_ws, size_t ws_size,
                              hipStream_t stream)
{
    (void)in_sizes; (void)n_in; (void)out_size; (void)ws_size; // needs >= 337 KB
    const float* x  = (const float*)d_in[0];
    const float* ir = (const float*)d_in[1];
    float* out      = (float*)d_out;
    ushort* tab     = (ushort*)d_ws;

    dim3 gt((NTAB + 255) / 256, 16);
    hipLaunchKernelGGL(build_tab, gt, dim3(256), 0, stream, ir, tab);

    dim3 grid((OUT_LEN + TM - 1) / TM);   // 489
    hipLaunchKernelGGL(spatialize_mfma6, grid, dim3(512), 0, stream, x, tab, out);
}